// Round 11
// baseline (207.454 us; speedup 1.0000x reference)
//
#include <hip/hip_runtime.h>

#define N_USER 50000
#define N_ITEM 50000
#define N_NODE 50000
#define N_EDGE 1600000
#define D 64

#define CB_SHIFT 8        // 256 nodes per coarse bucket
#define NBKT 196          // 196*256 = 50176 >= 50000
#define BCAP 10240        // per-bucket capacity (mean 8192, sigma~90 -> 22 sigma)
#define CHUNK 8192        // edges per chunk-sort block
#define NCH ((N_EDGE + CHUNK - 1) / CHUNK)     // 196
#define NCAST 3125        // cast blocks per table: 50000*16/256 exactly
#define SA_STR 36         // sA row stride (dwords): low bank aliasing

typedef __attribute__((ext_vector_type(8))) short short8;    // 8 bf16 = 4 VGPR
typedef __attribute__((ext_vector_type(4))) float floatx4;   // mfma acc

__device__ __forceinline__ unsigned short f32_to_bf16(float x) {
    unsigned u = __float_as_uint(x);
    unsigned r = (u + 0x7FFFu + ((u >> 16) & 1u)) >> 16;   // RNE
    return (unsigned short)r;
}
__device__ __forceinline__ unsigned pack2(float lo, float hi) {
    return (unsigned)f32_to_bf16(lo) | ((unsigned)f32_to_bf16(hi) << 16);
}

// accumulate one uint (2 packed bf16) into a[k], a[k+1] -- 2 bitops + 2 adds
__device__ __forceinline__ void acc2(float* a, int k, unsigned u) {
    a[k]     += __uint_as_float(u << 16);
    a[k + 1] += __uint_as_float(u & 0xFFFF0000u);
}
__device__ __forceinline__ void acc8(float* a, uint4 w) {
    acc2(a, 0, w.x); acc2(a, 2, w.y); acc2(a, 4, w.z); acc2(a, 6, w.w);
}

// ---------------------------------------------------------------------------
// Kernel 1 (merged): blocks [0, 2*NCH) chunk-sort 8192 edges each into coarse
// dst-buckets ENTIRELY IN LDS, then copy per-bucket segments to reserved
// contiguous windows in gbin (round-2 lesson: no scattered small global
// stores). Blocks [2*NCH, 2*NCH+2*NCAST) cast fp32->bf16 feature tables.
// Last 3 blocks: one-time W^T bf16 transposes (round-10 lesson: per-block W
// staging = bank conflicts + occupancy loss; precompute once instead).
// ---------------------------------------------------------------------------
__global__ __launch_bounds__(256) void cast_bin(
    const float4* __restrict__ fU, ushort4* __restrict__ bU,
    const float4* __restrict__ fI, ushort4* __restrict__ bI,
    const int* __restrict__ srcA, const int* __restrict__ dstA, unsigned* __restrict__ gbinA,
    const int* __restrict__ srcB, const int* __restrict__ dstB, unsigned* __restrict__ gbinB,
    int* __restrict__ fcur,
    const float* __restrict__ W_rev, const float* __restrict__ W_rate,
    const float* __restrict__ loop_w,
    unsigned short* __restrict__ wtRev, unsigned short* __restrict__ wtRate,
    unsigned short* __restrict__ wtLoop)
{
    __shared__ unsigned lbin[CHUNK];   // 32 KB staging
    __shared__ int hist[NBKT];
    __shared__ int lofs[NBKT];
    __shared__ int lcur[NBKT];
    __shared__ int gbase[NBKT];
    __shared__ int sc[256];

    const int id = blockIdx.x;

    if (id >= 2 * NCH + 2 * NCAST) {
        // W^T precompute role: Wt[n*64+k] = bf16(W[k*64+n])
        const int which = id - (2 * NCH + 2 * NCAST);
        const float* __restrict__ Wsrc = which == 0 ? W_rev : (which == 1 ? W_rate : loop_w);
        unsigned short* __restrict__ Wdst = which == 0 ? wtRev : (which == 1 ? wtRate : wtLoop);
        for (int i = threadIdx.x; i < 4096; i += 256)
            Wdst[i] = f32_to_bf16(Wsrc[(i & 63) * 64 + (i >> 6)]);
        return;
    }

    if (id >= 2 * NCH) {
        // cast role: pure streaming, exact bounds (NCAST*256 == N_NODE*16)
        const int cid = id - 2 * NCH;
        const int et = (cid >= NCAST) ? 1 : 0;
        const float4* __restrict__ in = et ? fI : fU;
        ushort4* __restrict__ out     = et ? bI : bU;
        int i = (cid - et * NCAST) * 256 + threadIdx.x;
        float4 v = in[i];
        ushort4 o;
        o.x = f32_to_bf16(v.x); o.y = f32_to_bf16(v.y);
        o.z = f32_to_bf16(v.z); o.w = f32_to_bf16(v.w);
        out[i] = o;
        return;
    }

    // chunk-sort role
    const int et = (id >= NCH) ? 1 : 0;
    const int chunk = id - et * NCH;
    const int* __restrict__ src = et ? srcB : srcA;
    const int* __restrict__ dst = et ? dstB : dstA;
    unsigned* __restrict__ gbin = et ? gbinB : gbinA;
    int* __restrict__ fc = fcur + et * NBKT;

    const int base = chunk * CHUNK;
    const int nE = min(CHUNK, N_EDGE - base);
    const int n4 = nE >> 2;                      // nE % 4 == 0 always here
    const int4* dst4 = (const int4*)(dst + base);
    const int4* src4 = (const int4*)(src + base);
    const int tid = threadIdx.x;

    for (int i = tid; i < NBKT; i += 256) hist[i] = 0;
    __syncthreads();

    // pass 1: count per coarse bucket
    for (int i = tid; i < n4; i += 256) {
        int4 d = dst4[i];
        atomicAdd(&hist[d.x >> CB_SHIFT], 1);
        atomicAdd(&hist[d.y >> CB_SHIFT], 1);
        atomicAdd(&hist[d.z >> CB_SHIFT], 1);
        atomicAdd(&hist[d.w >> CB_SHIFT], 1);
    }
    __syncthreads();

    // exclusive scan over 196 counts (256-wide Hillis-Steele)
    int v = (tid < NBKT) ? hist[tid] : 0;
    sc[tid] = v;
    __syncthreads();
    for (int o = 1; o < 256; o <<= 1) {
        int t = (tid >= o) ? sc[tid - o] : 0;
        __syncthreads();
        sc[tid] += t;
        __syncthreads();
    }
    if (tid < NBKT) {
        int excl = sc[tid] - v;
        lofs[tid] = excl;
        lcur[tid] = excl;
        // reserve contiguous global window for this chunk's segment
        gbase[tid] = v ? (tid * BCAP + atomicAdd(&fc[tid], v)) : 0;
    }
    __syncthreads();

    // pass 2: scatter packed (dst<<16)|src into LDS (re-read edges, L2-hot)
    for (int i = tid; i < n4; i += 256) {
        int4 d = dst4[i];
        int4 s = src4[i];
        { int p = atomicAdd(&lcur[d.x >> CB_SHIFT], 1); lbin[p] = ((unsigned)d.x << 16) | (unsigned)s.x; }
        { int p = atomicAdd(&lcur[d.y >> CB_SHIFT], 1); lbin[p] = ((unsigned)d.y << 16) | (unsigned)s.y; }
        { int p = atomicAdd(&lcur[d.z >> CB_SHIFT], 1); lbin[p] = ((unsigned)d.z << 16) | (unsigned)s.z; }
        { int p = atomicAdd(&lcur[d.w >> CB_SHIFT], 1); lbin[p] = ((unsigned)d.w << 16) | (unsigned)s.w; }
    }
    __syncthreads();

    // copy out: one wave per bucket segment, contiguous global writes
    const int wv = tid >> 6, ln = tid & 63;
    for (int b = wv; b < NBKT; b += 4) {
        const int s0 = lofs[b], c = hist[b], g = gbase[b];
        for (int t = ln; t < c; t += 64) gbin[g + t] = lbin[s0 + t];
    }
}

// ---------------------------------------------------------------------------
// Kernel 2 (FUSED bucket_sort + aggregate + GEMM): one block per
// (bucket, half, etype), 512 threads (8 waves).
// Phase A: counting-sort the bucket's gbin window into LDS lsrt -- no global
// srt/off/cnt arrays ever materialized (saves a dispatch + 13.6 MB traffic).
// Two blocks redundantly sort the same window (NSPLIT=2) so the grid stays
// at 784 blocks ~= 3 blocks/CU x 8 waves for gather MLP.
// Phase B: per 64-node round: register gather (8 lanes/node, uint4,
// unroll-8; indices from LDS) -> f32 mean -> LDS sA tile -> verified MFMA
// epilogue with B-fragments direct from global bf16 W^T (round-10 proven).
// ---------------------------------------------------------------------------
__global__ __launch_bounds__(512) void sort_agg_gemm(
    const uint4* __restrict__ userB, const uint4* __restrict__ itemB,
    const unsigned* __restrict__ gbinI, const unsigned* __restrict__ gbinU,
    const int* __restrict__ fcur,
    const unsigned short* __restrict__ wtRev, const float* __restrict__ b_rev,
    const unsigned short* __restrict__ wtRate, const float* __restrict__ b_rate,
    const unsigned short* __restrict__ wtLoop, const float* __restrict__ h_bias,
    float* __restrict__ out)
{
    const int et = blockIdx.y;   // 0: user-dst (rev edges), 1: item-dst (rate edges)
    const unsigned* __restrict__ gbin = et ? gbinI : gbinU;
    const uint4* __restrict__ tab     = et ? userB : itemB;   // gather sources
    const unsigned short* __restrict__ Wt = et ? wtRate : wtRev;
    const float* __restrict__ b_et    = et ? b_rate : b_rev;
    const unsigned short* __restrict__ feat =
        (const unsigned short*)(et ? itemB : userB);          // self-loop input
    float* __restrict__ outN = out + (et ? (size_t)N_USER * D : 0);

    const int b     = blockIdx.x >> 1;        // coarse bucket
    const int split = blockIdx.x & 1;         // which 128-node half we gather
    const int n = fcur[(et ? 0 : NBKT) + b];  // rate counts at [0,NBKT), rev at [NBKT,2*NBKT)
    const int startg = b * BCAP;
    const int nodebase = b << CB_SHIFT;
    const int tid = threadIdx.x;

    __shared__ unsigned short lsrt[BCAP];     // 20 KB sorted src ids
    __shared__ int scnt[256];                 // per-node count
    __shared__ int soff[256];                 // per-node exclusive offset
    __shared__ int pos[256];
    __shared__ int sc[256];
    __shared__ unsigned sA[64][SA_STR];       // 9 KB agg rows (packed bf16)

    // ---- phase A: counting sort into LDS ----
    if (tid < 256) scnt[tid] = 0;
    __syncthreads();

    for (int i = tid; i < n; i += 512)
        atomicAdd(&scnt[(int)(gbin[startg + i] >> 16) - nodebase], 1);
    __syncthreads();

    int v = 0;
    if (tid < 256) { v = scnt[tid]; sc[tid] = v; }
    __syncthreads();
    for (int o = 1; o < 256; o <<= 1) {
        int t = 0;
        if (tid < 256 && tid >= o) t = sc[tid - o];
        __syncthreads();
        if (tid < 256) sc[tid] += t;
        __syncthreads();
    }
    if (tid < 256) { soff[tid] = sc[tid] - v; pos[tid] = sc[tid] - v; }
    __syncthreads();

    for (int i = tid; i < n; i += 512) {
        unsigned p = gbin[startg + i];                  // L2-hot re-read
        int q = atomicAdd(&pos[(int)(p >> 16) - nodebase], 1);
        lsrt[q] = (unsigned short)(p & 0xFFFFu);
    }
    __syncthreads();

    // ---- phase B: gather + MFMA, 2 rounds of 64 nodes ----
    const int grp = tid >> 3;                 // 64 groups = 64 nodes/round
    const int dl  = tid & 7;                  // lane's uint4 within 128B row
    const int wave = tid >> 6, l = tid & 63, quad = l >> 4, l16 = l & 15;
    const int rowbase = (wave & 3) * 16;      // 4 row-tiles
    const int colbase = (wave >> 2) * 32;     // 2 col-halves

    for (int r = 0; r < 2; ++r) {
        const int lnode = split * 128 + r * 64 + grp;   // local node in bucket
        const int start = soff[lnode];
        const int c     = scnt[lnode];
        const int end   = start + c;

        float aA[8] = {0.f, 0.f, 0.f, 0.f, 0.f, 0.f, 0.f, 0.f};
        float aB[8] = {0.f, 0.f, 0.f, 0.f, 0.f, 0.f, 0.f, 0.f};

        int e = start;
        for (; e + 8 <= end; e += 8) {
            int s0 = (int)lsrt[e],     s1 = (int)lsrt[e + 1];
            int s2 = (int)lsrt[e + 2], s3 = (int)lsrt[e + 3];
            int s4 = (int)lsrt[e + 4], s5 = (int)lsrt[e + 5];
            int s6 = (int)lsrt[e + 6], s7 = (int)lsrt[e + 7];
            uint4 w0 = tab[(size_t)s0 * 8 + dl];
            uint4 w1 = tab[(size_t)s1 * 8 + dl];
            uint4 w2 = tab[(size_t)s2 * 8 + dl];
            uint4 w3 = tab[(size_t)s3 * 8 + dl];
            uint4 w4 = tab[(size_t)s4 * 8 + dl];
            uint4 w5 = tab[(size_t)s5 * 8 + dl];
            uint4 w6 = tab[(size_t)s6 * 8 + dl];
            uint4 w7 = tab[(size_t)s7 * 8 + dl];
            acc8(aA, w0); acc8(aB, w1); acc8(aA, w2); acc8(aB, w3);
            acc8(aA, w4); acc8(aB, w5); acc8(aA, w6); acc8(aB, w7);
        }
        for (; e + 4 <= end; e += 4) {
            int s0 = (int)lsrt[e],     s1 = (int)lsrt[e + 1];
            int s2 = (int)lsrt[e + 2], s3 = (int)lsrt[e + 3];
            uint4 w0 = tab[(size_t)s0 * 8 + dl];
            uint4 w1 = tab[(size_t)s1 * 8 + dl];
            uint4 w2 = tab[(size_t)s2 * 8 + dl];
            uint4 w3 = tab[(size_t)s3 * 8 + dl];
            acc8(aA, w0); acc8(aB, w1); acc8(aA, w2); acc8(aB, w3);
        }
        for (; e < end; ++e) {
            uint4 w = tab[(size_t)(int)lsrt[e] * 8 + dl];
            acc8(aA, w);
        }
        #pragma unroll
        for (int k = 0; k < 8; ++k) aA[k] += aB[k];

        const float inv = (c > 0) ? 1.0f / (float)c : 0.0f;
        sA[grp][dl * 4 + 0] = pack2(aA[0] * inv, aA[1] * inv);
        sA[grp][dl * 4 + 1] = pack2(aA[2] * inv, aA[3] * inv);
        sA[grp][dl * 4 + 2] = pack2(aA[4] * inv, aA[5] * inv);
        sA[grp][dl * 4 + 3] = pack2(aA[6] * inv, aA[7] * inv);
        __syncthreads();

        // MFMA epilogue: this round's 64 rows x 64 cols (verified layout)
        const int lrow = rowbase + l16;
        short8 aAgg0 = *(const short8*)&sA[lrow][     quad * 4];
        short8 aAgg1 = *(const short8*)&sA[lrow][16 + quad * 4];
        const int growb = nodebase + split * 128 + r * 64;
        const int grow = growb + lrow;
        const int gr = (grow < N_NODE) ? grow : (N_NODE - 1);
        short8 aFeat0 = *(const short8*)(feat + (size_t)gr * 64 +      quad * 8);
        short8 aFeat1 = *(const short8*)(feat + (size_t)gr * 64 + 32 + quad * 8);

        #pragma unroll
        for (int t = 0; t < 2; ++t) {
            const int nn = colbase + t * 16 + l16;
            short8 bW0 = *(const short8*)(Wt     + nn * 64 +      quad * 8);
            short8 bW1 = *(const short8*)(Wt     + nn * 64 + 32 + quad * 8);
            short8 bL0 = *(const short8*)(wtLoop + nn * 64 +      quad * 8);
            short8 bL1 = *(const short8*)(wtLoop + nn * 64 + 32 + quad * 8);
            floatx4 a = {0.f, 0.f, 0.f, 0.f};
            a = __builtin_amdgcn_mfma_f32_16x16x32_bf16(aAgg0,  bW0, a, 0, 0, 0);
            a = __builtin_amdgcn_mfma_f32_16x16x32_bf16(aAgg1,  bW1, a, 0, 0, 0);
            a = __builtin_amdgcn_mfma_f32_16x16x32_bf16(aFeat0, bL0, a, 0, 0, 0);
            a = __builtin_amdgcn_mfma_f32_16x16x32_bf16(aFeat1, bL1, a, 0, 0, 0);
            const float bh = h_bias[nn], be = b_et[nn];
            #pragma unroll
            for (int i = 0; i < 4; ++i) {
                const int rl = rowbase + quad * 4 + i;
                const int rglob = growb + rl;
                if (rglob < N_NODE) {
                    const int rc = scnt[split * 128 + r * 64 + rl];
                    outN[(size_t)rglob * D + nn] = a[i] + bh + (rc > 0 ? be : 0.f);
                }
            }
        }
        __syncthreads();   // before next round overwrites sA
    }
}

// ---------------------------------------------------------------------------
extern "C" void kernel_launch(void* const* d_in, const int* in_sizes, int n_in,
                              void* d_out, int out_size, void* d_ws, size_t ws_size,
                              hipStream_t stream)
{
    const float* user_feat = (const float*)d_in[0];
    const float* item_feat = (const float*)d_in[1];
    const int*   rate_src  = (const int*)d_in[2];
    const int*   rate_dst  = (const int*)d_in[3];
    const int*   rev_src   = (const int*)d_in[4];
    const int*   rev_dst   = (const int*)d_in[5];
    const float* W_rate    = (const float*)d_in[6];
    const float* b_rate    = (const float*)d_in[7];
    const float* W_rev     = (const float*)d_in[8];
    const float* b_rev     = (const float*)d_in[9];
    const float* loop_w    = (const float*)d_in[10];
    const float* h_bias    = (const float*)d_in[11];
    float* out = (float*)d_out;

    // workspace layout (~29 MB)
    char* p = (char*)d_ws;
    ushort4* userB = (ushort4*)p; p += (size_t)N_USER * D * 2;                 // 6.4 MB
    ushort4* itemB = (ushort4*)p; p += (size_t)N_ITEM * D * 2;                 // 6.4 MB
    unsigned* gbinI = (unsigned*)p; p += (size_t)NBKT * BCAP * 4;              // 8.0 MB
    unsigned* gbinU = (unsigned*)p; p += (size_t)NBKT * BCAP * 4;              // 8.0 MB
    int* fcur = (int*)p; p += (size_t)(2 * NBKT) * 4;                          // 1.6 KB
    unsigned short* wtRev  = (unsigned short*)p; p += 4096 * 2;                // 8 KB
    unsigned short* wtRate = (unsigned short*)p; p += 4096 * 2;                // 8 KB
    unsigned short* wtLoop = (unsigned short*)p; p += 4096 * 2;                // 8 KB
    (void)ws_size;

    // fcur = per-bucket fill counts, zero-init (1.6 KB)
    hipMemsetAsync(fcur, 0, (size_t)(2 * NBKT) * sizeof(int), stream);

    // 1) merged chunk-sort (blocks [0, 2*NCH), dispatched first)
    //    + cast (blocks [2*NCH, ...)) + 3 W^T precompute blocks (tail)
    cast_bin<<<dim3(2 * NCH + 2 * NCAST + 3), 256, 0, stream>>>(
        (const float4*)user_feat, userB, (const float4*)item_feat, itemB,
        rate_src, rate_dst, gbinI,
        rev_src,  rev_dst,  gbinU, fcur,
        W_rev, W_rate, loop_w, wtRev, wtRate, wtLoop);

    // 2) fused in-LDS bucket sort + segment-mean gather + dual GEMM epilogue
    sort_agg_gemm<<<dim3(NBKT * 2, 2), 512, 0, stream>>>(
        (const uint4*)userB, (const uint4*)itemB,
        gbinI, gbinU, fcur,
        wtRev, b_rev, wtRate, b_rate,
        wtLoop, h_bias, out);

    (void)in_sizes; (void)n_in; (void)out_size;
}